// Round 7
// baseline (16876.872 us; speedup 1.0000x reference)
//
#include <hip/hip_runtime.h>
#include <math.h>

typedef __attribute__((ext_vector_type(8))) short short8;
typedef __attribute__((ext_vector_type(4))) float floatx4;
typedef unsigned short ushort_t;
typedef unsigned int uint_t;

// Problem constants
constexpr int C_B   = 512;
constexpr int C_T   = 365;
constexpr int C_IN  = 10;
constexpr int C_H   = 256;
constexpr int C_OUT = 20;

// Packed B-plane layout (PROVEN in R5/R6): mat(3: Whh0,Wih1,Whh1) x plane(hi,lo)
// each plane = [48 nt][8 ks][64 lane][8] bf16, nt = jb*3 + gate.
constexpr size_t PLANE_U = 48ull * 8 * 64 * 8;      // 196608 ushorts
constexpr size_t PACK_B  = 6 * PLANE_U * 2;         // 2359296 bytes

__device__ __forceinline__ float fsig(float v)  { return 1.0f / (1.0f + __expf(-v)); }
__device__ __forceinline__ float ftanh(float v) { return 2.0f / (1.0f + __expf(-2.0f * v)) - 1.0f; }

__device__ __forceinline__ void split1(float x, ushort_t& hi, ushort_t& lo) {
    unsigned u = __float_as_uint(x);
    hi = (ushort_t)(u >> 16);
    float r = x - __uint_as_float(u & 0xffff0000u);
    lo = (ushort_t)(__float_as_uint(r) >> 16);
}

// ---------------- weight pack (verbatim from R6 — proven) ----------------
__global__ __launch_bounds__(256) void prep_pack(const float* __restrict__ Whh0,
                                                 const float* __restrict__ Wih1,
                                                 const float* __restrict__ Whh1,
                                                 ushort_t* __restrict__ PW) {
    const int blk = blockIdx.x;            // 144 = mat(3) x g(3) x jb(16)
    const int mat = blk / 48;
    const int rem = blk % 48;
    const int g   = rem / 16;
    const int jb  = rem % 16;
    const float* S = (mat == 0) ? Whh0 : (mat == 1) ? Wih1 : Whh1;

    const int tid = threadIdx.x;
    const int jl  = tid >> 4;
    const int kc  = tid & 15;
    const int j   = jb * 16 + jl;
    const int nt  = jb * 3 + g;

    const float* src = S + (g * 256 + j) * 256 + kc * 16;
    float f[16];
#pragma unroll
    for (int q = 0; q < 4; q++) {
        float4 v = *(const float4*)(src + q * 4);
        f[q*4+0] = v.x; f[q*4+1] = v.y; f[q*4+2] = v.z; f[q*4+3] = v.w;
    }
    ushort_t hi[16], lo[16];
#pragma unroll
    for (int e = 0; e < 16; e++) split1(f[e], hi[e], lo[e]);

    ushort_t* dhi = PW + (size_t)(mat * 2 + 0) * PLANE_U;
    ushort_t* dlo = PW + (size_t)(mat * 2 + 1) * PLANE_U;
    const int ks = kc >> 1;
#pragma unroll
    for (int hh = 0; hh < 2; hh++) {
        const int quad = (kc & 1) * 2 + hh;
        const int L    = quad * 16 + jl;
        const size_t base = ((size_t)(nt * 8 + ks)) * 512 + L * 8;
        short8 vh, vl;
#pragma unroll
        for (int e = 0; e < 8; e++) { vh[e] = (short)hi[hh*8+e]; vl[e] = (short)lo[hh*8+e]; }
        *(short8*)(dhi + base) = vh;
        *(short8*)(dlo + base) = vl;
    }
}

// ---------------- shared helpers ----------------
// Load this wave's 3 gate-tiles of one matrix into registers (192 VGPRs).
__device__ __forceinline__ void loadW(const ushort_t* __restrict__ PW, int matbase,
                                      int w, int lane, short8 wv[3][8][2]) {
    const ushort_t* ph = PW + (size_t)matbase * PLANE_U;
    const ushort_t* pl = ph + PLANE_U;
#pragma unroll
    for (int g = 0; g < 3; g++)
#pragma unroll
        for (int ks = 0; ks < 8; ks++) {
            const size_t off = ((size_t)((3 * w + g) * 8 + ks)) * 512 + lane * 8;
            wv[g][ks][0] = *(const short8*)(ph + off);
            wv[g][ks][1] = *(const short8*)(pl + off);
        }
}

// A-fragments (16 rows x K=256) from LDS hi/lo planes (stride 264 ushorts).
__device__ __forceinline__ void loadA(const ushort_t* Phi, const ushort_t* Plo,
                                      int lane, short8 Ah[8], short8 Al[8]) {
    const int m = lane & 15, q = lane >> 4;
    const int base = m * 264 + q * 8;
#pragma unroll
    for (int ks = 0; ks < 8; ks++) {
        Ah[ks] = *(const short8*)(Phi + base + ks * 32);
        Al[ks] = *(const short8*)(Plo + base + ks * 32);
    }
}

// Stage a packed-uint [16][256] global tile into LDS hi/lo planes (1024 thr).
__device__ __forceinline__ void stageState(const uint_t* __restrict__ src,
                                           ushort_t* Phi, ushort_t* Plo, int tid) {
    uint4 v = ((const uint4*)src)[tid];
    const int row = tid >> 6, col = (tid & 63) * 4;
    ushort_t* ph = Phi + row * 264 + col;
    ushort_t* pl = Plo + row * 264 + col;
    ph[0] = (ushort_t)(v.x >> 16); pl[0] = (ushort_t)v.x;
    ph[1] = (ushort_t)(v.y >> 16); pl[1] = (ushort_t)v.y;
    ph[2] = (ushort_t)(v.z >> 16); pl[2] = (ushort_t)v.z;
    ph[3] = (ushort_t)(v.w >> 16); pl[3] = (ushort_t)v.w;
}

__device__ __forceinline__ float ldplane(const ushort_t* Phi, const ushort_t* Plo,
                                         int row, int j) {
    return __uint_as_float(((uint_t)Phi[row * 264 + j]) << 16) +
           __uint_as_float(((uint_t)Plo[row * 264 + j]) << 16);
}

// 72 MFMA: 3 gate-tiles x 8 ksteps x 3-pass split-bf16 (fp32-equivalent).
__device__ __forceinline__ void mm72(const short8 Ah[8], const short8 Al[8],
                                     const short8 wv[3][8][2], floatx4 acc[3]) {
#pragma unroll
    for (int ks = 0; ks < 8; ks++)
#pragma unroll
        for (int g = 0; g < 3; g++) {
            acc[g] = __builtin_amdgcn_mfma_f32_16x16x32_bf16(Ah[ks], wv[g][ks][0], acc[g], 0, 0, 0);
            acc[g] = __builtin_amdgcn_mfma_f32_16x16x32_bf16(Al[ks], wv[g][ks][0], acc[g], 0, 0, 0);
            acc[g] = __builtin_amdgcn_mfma_f32_16x16x32_bf16(Ah[ks], wv[g][ks][1], acc[g], 0, 0, 0);
        }
}

// ---------------- layer 0: persistent recurrence, Whh0 in registers ----------------
__global__ __launch_bounds__(1024, 1) void layer0_run(
    const float* __restrict__ x, const float* __restrict__ Wih0,
    const float* __restrict__ bih0, const float* __restrict__ bhh0,
    const ushort_t* __restrict__ PW, uint_t* __restrict__ h0chunk,
    const uint_t* __restrict__ prevlast, int t0, int tau)
{
    __shared__ ushort_t Phi[16 * 264], Plo[16 * 264];
    __shared__ float xs[16][C_IN];
    const int tid = threadIdx.x, lane = tid & 63, w = tid >> 6;
    const int jlo = lane & 15, quad = lane >> 4;
    const int b0 = blockIdx.x * 16;
    const int j = w * 16 + jlo;

    short8 wv[3][8][2];
    loadW(PW, 0, w, lane, wv);                 // Whh0
    float wxr[C_IN], wxz[C_IN], wxn[C_IN];
#pragma unroll
    for (int i = 0; i < C_IN; i++) {
        wxr[i] = Wih0[j * C_IN + i];
        wxz[i] = Wih0[(256 + j) * C_IN + i];
        wxn[i] = Wih0[(512 + j) * C_IN + i];
    }
    const float b_r = bih0[j] + bhh0[j];
    const float b_z = bih0[256 + j] + bhh0[256 + j];
    const float b_in = bih0[512 + j];
    const float b_hn = bhh0[512 + j];

    short8 Ah[8], Al[8];
    if (t0 > 0) {
        stageState(prevlast + b0 * 256, Phi, Plo, tid);
        __syncthreads();
        loadA(Phi, Plo, lane, Ah, Al);
    }

    for (int tc = 0; tc < tau; tc++) {
        const int tg = t0 + tc;
        if (tid < 16 * C_IN) {
            int r = tid / C_IN, c = tid - r * C_IN;
            xs[r][c] = x[(size_t)(b0 + r) * (C_T * C_IN) + tg * C_IN + c];
        }
        floatx4 acc[3] = {{0,0,0,0},{0,0,0,0},{0,0,0,0}};
        if (tg > 0) mm72(Ah, Al, wv, acc);
        __syncthreads();   // xs ready; all A-frag LDS reads drained before plane overwrite
#pragma unroll
        for (int rr = 0; rr < 4; rr++) {
            const int row = quad * 4 + rr;
            float xr = 0.f, xz = 0.f, xn = 0.f;
#pragma unroll
            for (int i = 0; i < C_IN; i++) {
                float xv = xs[row][i];
                xr += xv * wxr[i]; xz += xv * wxz[i]; xn += xv * wxn[i];
            }
            float hp = (tg > 0) ? ldplane(Phi, Plo, row, j) : 0.f;
            const float ar = acc[0][rr] + xr + b_r;
            const float az = acc[1][rr] + xz + b_z;
            const float rg = fsig(ar), zg = fsig(az);
            const float nn = ftanh(xn + b_in + rg * (acc[2][rr] + b_hn));
            const float hv = zg * (hp - nn) + nn;
            ushort_t hi, lo; split1(hv, hi, lo);
            h0chunk[(size_t)tc * 131072 + (size_t)(b0 + row) * 256 + j] = ((uint_t)hi << 16) | lo;
            Phi[row * 264 + j] = hi;
            Plo[row * 264 + j] = lo;
        }
        __syncthreads();
        loadA(Phi, Plo, lane, Ah, Al);         // h0_t -> A-frags for next step
    }
}

// ---------------- gi1 GEMM: all-parallel over t, Wih1 in registers ----------------
__global__ __launch_bounds__(1024, 1) void gi_gemm(
    const ushort_t* __restrict__ PW, const uint_t* __restrict__ h0chunk,
    float* __restrict__ gichunk, int ntiles)
{
    __shared__ uint_t At[16 * 268];
    const int tid = threadIdx.x, lane = tid & 63, w = tid >> 6;
    const int jlo = lane & 15, quad = lane >> 4;

    short8 wv[3][8][2];
    loadW(PW, 2, w, lane, wv);                 // Wih1

    for (int tile = blockIdx.x; tile < ntiles; tile += 256) {
        const int tc = tile >> 5, mt = tile & 31;
        __syncthreads();                       // prior readers of At are done
        {
            uint4 v = ((const uint4*)(h0chunk + (size_t)tc * 131072 + mt * 4096))[tid];
            const int row = tid >> 6, col = (tid & 63) * 4;
            *(uint4*)(At + row * 268 + col) = v;
        }
        __syncthreads();
        floatx4 acc[3] = {{0,0,0,0},{0,0,0,0},{0,0,0,0}};
        const int m = lane & 15, q = lane >> 4;
#pragma unroll
        for (int ks = 0; ks < 8; ks++) {
            const uint_t* p = At + m * 268 + q * 8 + ks * 32;
            uint4 u0 = *(const uint4*)p;
            uint4 u1 = *(const uint4*)(p + 4);
            short8 Ah, Al;
            Ah[0]=(short)(u0.x>>16); Al[0]=(short)u0.x;
            Ah[1]=(short)(u0.y>>16); Al[1]=(short)u0.y;
            Ah[2]=(short)(u0.z>>16); Al[2]=(short)u0.z;
            Ah[3]=(short)(u0.w>>16); Al[3]=(short)u0.w;
            Ah[4]=(short)(u1.x>>16); Al[4]=(short)u1.x;
            Ah[5]=(short)(u1.y>>16); Al[5]=(short)u1.y;
            Ah[6]=(short)(u1.z>>16); Al[6]=(short)u1.z;
            Ah[7]=(short)(u1.w>>16); Al[7]=(short)u1.w;
#pragma unroll
            for (int g = 0; g < 3; g++) {
                acc[g] = __builtin_amdgcn_mfma_f32_16x16x32_bf16(Ah, wv[g][ks][0], acc[g], 0, 0, 0);
                acc[g] = __builtin_amdgcn_mfma_f32_16x16x32_bf16(Al, wv[g][ks][0], acc[g], 0, 0, 0);
                acc[g] = __builtin_amdgcn_mfma_f32_16x16x32_bf16(Ah, wv[g][ks][1], acc[g], 0, 0, 0);
            }
        }
#pragma unroll
        for (int g = 0; g < 3; g++)
#pragma unroll
            for (int rr = 0; rr < 4; rr++)
                gichunk[(size_t)tc * 393216 + (size_t)(mt * 16 + quad * 4 + rr) * 768
                        + g * 256 + w * 16 + jlo] = acc[g][rr];
    }
}

// ---------------- layer 1 (gi path): persistent recurrence, Whh1 in registers ----------------
__global__ __launch_bounds__(1024, 1) void layer1_gi(
    const ushort_t* __restrict__ PW, const float* __restrict__ gichunk,
    uint_t* __restrict__ h1state, const float* __restrict__ bih1,
    const float* __restrict__ bhh1, float* __restrict__ H1F, int t0, int tau)
{
    __shared__ ushort_t Phi[16 * 264], Plo[16 * 264];
    const int tid = threadIdx.x, lane = tid & 63, w = tid >> 6;
    const int jlo = lane & 15, quad = lane >> 4;
    const int b0 = blockIdx.x * 16;
    const int j = w * 16 + jlo;

    short8 wv[3][8][2];
    loadW(PW, 4, w, lane, wv);                 // Whh1
    const float b_r = bih1[j] + bhh1[j];
    const float b_z = bih1[256 + j] + bhh1[256 + j];
    const float b_in = bih1[512 + j];
    const float b_hn = bhh1[512 + j];

    short8 Ah[8], Al[8];
    if (t0 > 0) {
        stageState(h1state + b0 * 256, Phi, Plo, tid);
        __syncthreads();
        loadA(Phi, Plo, lane, Ah, Al);
    }

    for (int tc = 0; tc < tau; tc++) {
        const int tg = t0 + tc;
        float gr[4], gz[4], gn[4];
#pragma unroll
        for (int rr = 0; rr < 4; rr++) {
            const size_t base = (size_t)tc * 393216 + (size_t)(b0 + quad * 4 + rr) * 768 + j;
            gr[rr] = gichunk[base];
            gz[rr] = gichunk[base + 256];
            gn[rr] = gichunk[base + 512];
        }
        floatx4 acc[3] = {{0,0,0,0},{0,0,0,0},{0,0,0,0}};
        if (tg > 0) mm72(Ah, Al, wv, acc);
        __syncthreads();
#pragma unroll
        for (int rr = 0; rr < 4; rr++) {
            const int row = quad * 4 + rr;
            float hp = (tg > 0) ? ldplane(Phi, Plo, row, j) : 0.f;
            const float ar = acc[0][rr] + gr[rr] + b_r;
            const float az = acc[1][rr] + gz[rr] + b_z;
            const float rg = fsig(ar), zg = fsig(az);
            const float nn = ftanh(gn[rr] + b_in + rg * (acc[2][rr] + b_hn));
            const float hv = zg * (hp - nn) + nn;
            ushort_t hi, lo; split1(hv, hi, lo);
            Phi[row * 264 + j] = hi;
            Plo[row * 264 + j] = lo;
            if (tc == tau - 1) {
                h1state[(b0 + row) * 256 + j] = ((uint_t)hi << 16) | lo;
                H1F[(b0 + row) * 256 + j] = hv;
            }
        }
        __syncthreads();
        loadA(Phi, Plo, lane, Ah, Al);
    }
}

// ---------------- layer 1 (no-gi fallback): Wih1+Whh1 both in registers ----------------
__global__ __launch_bounds__(1024, 1) void layer1_nogi(
    const ushort_t* __restrict__ PW, const uint_t* __restrict__ h0chunk,
    uint_t* __restrict__ h1state, const float* __restrict__ bih1,
    const float* __restrict__ bhh1, float* __restrict__ H1F, int t0, int tau)
{
    __shared__ ushort_t Ghi[16 * 264], Glo[16 * 264];
    __shared__ ushort_t Hhi[16 * 264], Hlo[16 * 264];
    const int tid = threadIdx.x, lane = tid & 63, w = tid >> 6;
    const int jlo = lane & 15, quad = lane >> 4;
    const int b0 = blockIdx.x * 16;
    const int j = w * 16 + jlo;

    short8 wvI[3][8][2], wvH[3][8][2];
    loadW(PW, 2, w, lane, wvI);                // Wih1
    loadW(PW, 4, w, lane, wvH);                // Whh1
    const float b_r = bih1[j] + bhh1[j];
    const float b_z = bih1[256 + j] + bhh1[256 + j];
    const float b_in = bih1[512 + j];
    const float b_hn = bhh1[512 + j];

    short8 Ah[8], Al[8];
    if (t0 > 0) {
        stageState(h1state + b0 * 256, Hhi, Hlo, tid);
        __syncthreads();
        loadA(Hhi, Hlo, lane, Ah, Al);
    }

    for (int tc = 0; tc < tau; tc++) {
        const int tg = t0 + tc;
        floatx4 aR = {0,0,0,0}, aZ = {0,0,0,0}, aIN = {0,0,0,0}, aHN = {0,0,0,0};
        if (tg > 0) {                          // gh pass over h1_prev (A = h1 frags)
#pragma unroll
            for (int ks = 0; ks < 8; ks++) {
                aR  = __builtin_amdgcn_mfma_f32_16x16x32_bf16(Ah[ks], wvH[0][ks][0], aR, 0, 0, 0);
                aR  = __builtin_amdgcn_mfma_f32_16x16x32_bf16(Al[ks], wvH[0][ks][0], aR, 0, 0, 0);
                aR  = __builtin_amdgcn_mfma_f32_16x16x32_bf16(Ah[ks], wvH[0][ks][1], aR, 0, 0, 0);
                aZ  = __builtin_amdgcn_mfma_f32_16x16x32_bf16(Ah[ks], wvH[1][ks][0], aZ, 0, 0, 0);
                aZ  = __builtin_amdgcn_mfma_f32_16x16x32_bf16(Al[ks], wvH[1][ks][0], aZ, 0, 0, 0);
                aZ  = __builtin_amdgcn_mfma_f32_16x16x32_bf16(Ah[ks], wvH[1][ks][1], aZ, 0, 0, 0);
                aHN = __builtin_amdgcn_mfma_f32_16x16x32_bf16(Ah[ks], wvH[2][ks][0], aHN, 0, 0, 0);
                aHN = __builtin_amdgcn_mfma_f32_16x16x32_bf16(Al[ks], wvH[2][ks][0], aHN, 0, 0, 0);
                aHN = __builtin_amdgcn_mfma_f32_16x16x32_bf16(Ah[ks], wvH[2][ks][1], aHN, 0, 0, 0);
            }
        }
        stageState(h0chunk + (size_t)tc * 131072 + b0 * 256, Ghi, Glo, tid);
        __syncthreads();                       // S1
        loadA(Ghi, Glo, lane, Ah, Al);         // A = h0_t frags
#pragma unroll
        for (int ks = 0; ks < 8; ks++) {
            aR  = __builtin_amdgcn_mfma_f32_16x16x32_bf16(Ah[ks], wvI[0][ks][0], aR, 0, 0, 0);
            aR  = __builtin_amdgcn_mfma_f32_16x16x32_bf16(Al[ks], wvI[0][ks][0], aR, 0, 0, 0);
            aR  = __builtin_amdgcn_mfma_f32_16x16x32_bf16(Ah[ks], wvI[0][ks][1], aR, 0, 0, 0);
            aZ  = __builtin_amdgcn_mfma_f32_16x16x32_bf16(Ah[ks], wvI[1][ks][0], aZ, 0, 0, 0);
            aZ  = __builtin_amdgcn_mfma_f32_16x16x32_bf16(Al[ks], wvI[1][ks][0], aZ, 0, 0, 0);
            aZ  = __builtin_amdgcn_mfma_f32_16x16x32_bf16(Ah[ks], wvI[1][ks][1], aZ, 0, 0, 0);
            aIN = __builtin_amdgcn_mfma_f32_16x16x32_bf16(Ah[ks], wvI[2][ks][0], aIN, 0, 0, 0);
            aIN = __builtin_amdgcn_mfma_f32_16x16x32_bf16(Al[ks], wvI[2][ks][0], aIN, 0, 0, 0);
            aIN = __builtin_amdgcn_mfma_f32_16x16x32_bf16(Ah[ks], wvI[2][ks][1], aIN, 0, 0, 0);
        }
#pragma unroll
        for (int rr = 0; rr < 4; rr++) {
            const int row = quad * 4 + rr;
            float hp = (tg > 0) ? ldplane(Hhi, Hlo, row, j) : 0.f;
            const float ar = aR[rr] + b_r;
            const float az = aZ[rr] + b_z;
            const float rg = fsig(ar), zg = fsig(az);
            const float nn = ftanh(aIN[rr] + b_in + rg * (aHN[rr] + b_hn));
            const float hv = zg * (hp - nn) + nn;
            ushort_t hi, lo; split1(hv, hi, lo);
            Hhi[row * 264 + j] = hi;
            Hlo[row * 264 + j] = lo;
            if (tc == tau - 1) {
                h1state[(b0 + row) * 256 + j] = ((uint_t)hi << 16) | lo;
                H1F[(b0 + row) * 256 + j] = hv;
            }
        }
        __syncthreads();                       // S2
        loadA(Hhi, Hlo, lane, Ah, Al);         // A = h1_t frags for next step
    }
}

// ---------------- classifier + softmax (fp32 h1 input) ----------------
__global__ __launch_bounds__(256) void classifier_f32(
    const float* __restrict__ h1,
    const float* __restrict__ Wout, const float* __restrict__ bout,
    float* __restrict__ out)
{
    __shared__ float hs[32][C_H + 4];
    __shared__ float lg[32 * C_OUT];
    const int tid = threadIdx.x;
    const int b0  = blockIdx.x * 32;
#pragma unroll
    for (int i = 0; i < 32; i++) hs[i][tid] = h1[(b0 + i) * C_H + tid];
    __syncthreads();
    for (int u = tid; u < 32 * C_OUT; u += 256) {
        int bb = u / C_OUT, o = u - bb * C_OUT;
        const float* wr = Wout + o * C_H;
        float acc = bout[o];
#pragma unroll 4
        for (int k = 0; k < C_H; k += 4) {
            float4 wv = *(const float4*)(wr + k);
            float4 hv = *(const float4*)(&hs[bb][k]);
            acc += wv.x*hv.x + wv.y*hv.y + wv.z*hv.z + wv.w*hv.w;
        }
        lg[u] = acc;
    }
    __syncthreads();
    if (tid < 32) {
        float mx = -1e30f;
#pragma unroll
        for (int o = 0; o < C_OUT; o++) mx = fmaxf(mx, lg[tid * C_OUT + o]);
        float e[C_OUT];
        float s = 0.0f;
#pragma unroll
        for (int o = 0; o < C_OUT; o++) { e[o] = __expf(lg[tid * C_OUT + o] - mx); s += e[o]; }
        float inv = 1.0f / s;
#pragma unroll
        for (int o = 0; o < C_OUT; o++) out[(b0 + tid) * C_OUT + o] = e[o] * inv;
    }
}

extern "C" void kernel_launch(void* const* d_in, const int* in_sizes, int n_in,
                              void* d_out, int out_size, void* d_ws, size_t ws_size,
                              hipStream_t stream) {
    const float* x    = (const float*)d_in[0];
    // d_in[1] = times (unused), d_in[2] = interpolation_method (unused)
    const float* Wih0 = (const float*)d_in[3];
    const float* Whh0 = (const float*)d_in[4];
    const float* bih0 = (const float*)d_in[5];
    const float* bhh0 = (const float*)d_in[6];
    const float* Wih1 = (const float*)d_in[7];
    const float* Whh1 = (const float*)d_in[8];
    const float* bih1 = (const float*)d_in[9];
    const float* bhh1 = (const float*)d_in[10];
    const float* Wout = (const float*)d_in[11];
    const float* bout = (const float*)d_in[12];
    float* out = (float*)d_out;

    char* base = (char*)d_ws;
    ushort_t* PW      = (ushort_t*)base;
    uint_t*   h1state = (uint_t*)(base + PACK_B);
    float*    H1F     = (float*)(base + PACK_B + 524288);
    char*     dyn     = base + PACK_B + 1048576;
    const size_t fixed_end = PACK_B + 1048576;
    const size_t avail = (ws_size > fixed_end) ? (ws_size - fixed_end) : 0;

    // Adaptive chunking: GI path needs tau*(512KB h0 + 1.5MB gi); NOGI needs tau*512KB.
    long tau_gi = (long)(avail / (524288 + 1572864));
    int use_gi, tau;
    if (tau_gi >= 4) {
        use_gi = 1;
        tau = (tau_gi > 128) ? 128 : (int)tau_gi;
    } else {
        use_gi = 0;
        long tn = (long)(avail / 524288);
        tau = (tn >= 1) ? (int)tn : 1;
        if (tau > C_T) tau = C_T;
    }
    if (tau > C_T) tau = C_T;

    prep_pack<<<144, 256, 0, stream>>>(Whh0, Wih1, Whh1, PW);

    uint_t* h0chunk = (uint_t*)dyn;
    float*  gichunk = (float*)(dyn + (size_t)tau * 524288);

    int prev_tc = 0;
    for (int t0 = 0; t0 < C_T; ) {
        int tc = (C_T - t0 < tau) ? (C_T - t0) : tau;
        const uint_t* prevlast = h0chunk + (size_t)((prev_tc > 0) ? prev_tc - 1 : 0) * 131072;
        layer0_run<<<32, 1024, 0, stream>>>(x, Wih0, bih0, bhh0, PW, h0chunk, prevlast, t0, tc);
        if (use_gi) {
            gi_gemm<<<256, 1024, 0, stream>>>(PW, h0chunk, gichunk, 32 * tc);
            layer1_gi<<<32, 1024, 0, stream>>>(PW, gichunk, h1state, bih1, bhh1, H1F, t0, tc);
        } else {
            layer1_nogi<<<32, 1024, 0, stream>>>(PW, h0chunk, h1state, bih1, bhh1, H1F, t0, tc);
        }
        prev_tc = tc;
        t0 += tc;
    }
    classifier_f32<<<C_B / 32, 256, 0, stream>>>(H1F, Wout, bout, out);
}